// Round 1
// baseline (2327.693 us; speedup 1.0000x reference)
//
#include <hip/hip_runtime.h>
#include <math.h>

#define N_NODES 65536
#define NPG     4096
#define D_IN    34
#define EMB     34
#define S_DIM   4
#define P_DIM   22
#define CONCAT  78      // EMB + 2*P_DIM
#define WIDTH   126
#define WPAD    128
#define KNN     8
#define HPAD    24      // padded h row (22 -> 24, keeps 16B alignment)
#define EPAD    36      // padded emb row (34 -> 36)

__device__ __forceinline__ float elu1(float v) {
    return v > 0.f ? v : expm1f(v);
}

// ---------------------------------------------------------------------------
// s = emb @ Ws + bs   [N,4];   h = emb @ Wh + bh   [N,22] (stored padded to 24)
// ---------------------------------------------------------------------------
__global__ __launch_bounds__(256) void sh_kernel(
        const float* __restrict__ emb, int eld,
        const float* __restrict__ Ws, const float* __restrict__ bs,
        const float* __restrict__ Wh, const float* __restrict__ bh,
        float* __restrict__ s_out, float* __restrict__ h_out) {
    __shared__ float lWs[EMB * S_DIM];
    __shared__ float lWh[EMB * P_DIM];
    __shared__ float lbs[S_DIM];
    __shared__ float lbh[P_DIM];
    for (int t = threadIdx.x; t < EMB * S_DIM; t += 256) lWs[t] = Ws[t];
    for (int t = threadIdx.x; t < EMB * P_DIM; t += 256) lWh[t] = Wh[t];
    if (threadIdx.x < S_DIM) lbs[threadIdx.x] = bs[threadIdx.x];
    if (threadIdx.x < P_DIM) lbh[threadIdx.x] = bh[threadIdx.x];
    __syncthreads();

    const int n = blockIdx.x * 256 + threadIdx.x;
    const float* __restrict__ row = emb + (size_t)n * eld;
    float e[EMB];
#pragma unroll
    for (int r = 0; r < EMB; ++r) e[r] = row[r];

    float s[S_DIM], h[P_DIM];
#pragma unroll
    for (int c = 0; c < S_DIM; ++c) s[c] = lbs[c];
#pragma unroll
    for (int c = 0; c < P_DIM; ++c) h[c] = lbh[c];
#pragma unroll
    for (int r = 0; r < EMB; ++r) {
        const float er = e[r];
#pragma unroll
        for (int c = 0; c < S_DIM; ++c) s[c] = fmaf(er, lWs[r * S_DIM + c], s[c]);
#pragma unroll
        for (int c = 0; c < P_DIM; ++c) h[c] = fmaf(er, lWh[r * P_DIM + c], h[c]);
    }
    ((float4*)s_out)[n] = make_float4(s[0], s[1], s[2], s[3]);
    float* __restrict__ hr = h_out + (size_t)n * HPAD;
#pragma unroll
    for (int c = 0; c < P_DIM; ++c) hr[c] = h[c];
}

// ---------------------------------------------------------------------------
// GravNet core: per-graph brute-force kNN (k=8) in LDS-staged 4-d space,
// exp(-10 d2) weighted mean/max aggregation, fused output GEMM (concat @ Wo).
// grid = 16 graphs * 16 chunks; block = 256 threads (1 node / thread).
// ---------------------------------------------------------------------------
__global__ __launch_bounds__(256, 2) void grav_kernel(
        const float* __restrict__ emb_in, int eld,
        const float* __restrict__ s_buf,
        const float* __restrict__ h_buf,
        const float* __restrict__ Wo, const float* __restrict__ bo,
        float* __restrict__ emb_out) {
    __shared__ float4 sl[NPG];            // 64 KB: graph's learned-space coords
    __shared__ float  wot[EMB * 80];      // Wo^T, rows padded 78 -> 80
    __shared__ float  bol[EMB];

    const int g = blockIdx.x >> 4;
    const int chunk = blockIdx.x & 15;
    const int gbase = g * NPG;

    const float4* __restrict__ sg = (const float4*)s_buf + gbase;
    for (int t = threadIdx.x; t < NPG; t += 256) sl[t] = sg[t];
    for (int t = threadIdx.x; t < CONCAT * EMB; t += 256) {
        const int r = t / EMB, c = t % EMB;
        wot[c * 80 + r] = Wo[t];
    }
    if (threadIdx.x < EMB) bol[threadIdx.x] = bo[threadIdx.x];
    __syncthreads();

    const int il = chunk * 256 + threadIdx.x;   // node index within graph
    const float4 si = sl[il];

    // sorted top-8 (descending; d[0] = current 8th-smallest threshold)
    float d[KNN]; int nb[KNN];
#pragma unroll
    for (int r = 0; r < KNN; ++r) { d[r] = 3.4e38f; nb[r] = 0; }

#pragma unroll 4
    for (int j = 0; j < NPG; ++j) {
        const float4 sj = sl[j];                 // wave-uniform LDS broadcast
        const float dx = si.x - sj.x, dy = si.y - sj.y;
        const float dz = si.z - sj.z, dw = si.w - sj.w;
        const float d2 = fmaf(dx, dx, fmaf(dy, dy, fmaf(dz, dz, dw * dw)));
        if (d2 < d[0]) {
            float cv = d2; int ci = j;           // sift-insert (branchless body)
#pragma unroll
            for (int r = 0; r < KNN - 1; ++r) {
                const float nx = d[r + 1]; const int ni = nb[r + 1];
                const bool c = cv < nx;
                d[r]  = c ? nx : cv;
                nb[r] = c ? ni : ci;
                cv    = c ? cv : nx;
                ci    = c ? ci : ni;
            }
            d[KNN - 1] = cv; nb[KNN - 1] = ci;
        }
    }

    float w8[KNN];
#pragma unroll
    for (int r = 0; r < KNN; ++r) w8[r] = expf(-10.f * d[r]);

    float mean[P_DIM], mx[P_DIM];
#pragma unroll
    for (int c = 0; c < P_DIM; ++c) { mean[c] = 0.f; mx[c] = -3.4e38f; }

#pragma unroll
    for (int r = 0; r < KNN; ++r) {
        const float w = w8[r];
        const float4* __restrict__ hrow =
            (const float4*)(h_buf + (size_t)(gbase + nb[r]) * HPAD);
        const float4 q0 = hrow[0], q1 = hrow[1], q2 = hrow[2];
        const float4 q3 = hrow[3], q4 = hrow[4], q5 = hrow[5];
#define AGG(c, val) { const float m = w * (val); mean[c] += m; mx[c] = fmaxf(mx[c], m); }
        AGG(0, q0.x) AGG(1, q0.y) AGG(2, q0.z) AGG(3, q0.w)
        AGG(4, q1.x) AGG(5, q1.y) AGG(6, q1.z) AGG(7, q1.w)
        AGG(8, q2.x) AGG(9, q2.y) AGG(10, q2.z) AGG(11, q2.w)
        AGG(12, q3.x) AGG(13, q3.y) AGG(14, q3.z) AGG(15, q3.w)
        AGG(16, q4.x) AGG(17, q4.y) AGG(18, q4.z) AGG(19, q4.w)
        AGG(20, q5.x) AGG(21, q5.y)
#undef AGG
    }
#pragma unroll
    for (int c = 0; c < P_DIM; ++c) mean[c] *= 0.125f;

    // fused out = [emb | mean | max] @ Wo + bo
    const int nglob = gbase + il;
    const float* __restrict__ erow = emb_in + (size_t)nglob * eld;
    float e[EMB];
#pragma unroll
    for (int r = 0; r < EMB; ++r) e[r] = erow[r];

    float* __restrict__ orow = emb_out + (size_t)nglob * EPAD;
    for (int c = 0; c < EMB; ++c) {
        const float* __restrict__ wr = &wot[c * 80];
        float acc = bol[c];
#pragma unroll
        for (int r = 0; r < EMB; ++r)  acc = fmaf(e[r], wr[r], acc);
#pragma unroll
        for (int p = 0; p < P_DIM; ++p) acc = fmaf(mean[p], wr[34 + p], acc);
#pragma unroll
        for (int p = 0; p < P_DIM; ++p) acc = fmaf(mx[p], wr[56 + p], acc);
        orow[c] = acc;
    }
}

// ---------------------------------------------------------------------------
// transpose + zero-pad weight into [OPAD rows][KPAD cols]:
// dst[o*KPAD + k] = (k<K && o<O) ? src[k*O + o] : 0
// ---------------------------------------------------------------------------
__global__ void prep_wt(const float* __restrict__ src, float* __restrict__ dst,
                        int K, int O, int KPAD, int total) {
    const int t = blockIdx.x * 256 + threadIdx.x;
    if (t >= total) return;
    const int o = t / KPAD, k = t % KPAD;
    dst[t] = (k < K && o < O) ? src[k * O + o] : 0.f;
}

// ---------------------------------------------------------------------------
// Dense layer: out[N,128] = act(in[N,:K] @ W + b). W^T staged in LDS,
// one row/thread, 128 register accumulators, b128 broadcast weight reads.
// ---------------------------------------------------------------------------
template <int K4, int KTAIL, int KPAD, bool DOELU>
__global__ __launch_bounds__(128, 2) void mlp_layer(
        const float* __restrict__ in, int ild,
        const float* __restrict__ wt,     // [WPAD][KPAD], transposed+padded
        const float* __restrict__ bias,   // [WIDTH]
        float* __restrict__ out) {
    __shared__ float lwt[WPAD * KPAD];
    __shared__ float lb[WPAD];
    for (int t = threadIdx.x; t < WPAD * KPAD / 4; t += 128)
        ((float4*)lwt)[t] = ((const float4*)wt)[t];
    if (threadIdx.x < WPAD)
        lb[threadIdx.x] = (threadIdx.x < WIDTH) ? bias[threadIdx.x] : 0.f;
    __syncthreads();

    const int row = blockIdx.x * 128 + threadIdx.x;
    const float* __restrict__ xr = in + (size_t)row * ild;

    float acc[WPAD];
#pragma unroll
    for (int o = 0; o < WPAD; ++o) acc[o] = lb[o];

    for (int k4 = 0; k4 < K4; ++k4) {
        const int k = k4 * 4;
        const float x0 = xr[k + 0], x1 = xr[k + 1];
        const float x2 = xr[k + 2], x3 = xr[k + 3];
#pragma unroll
        for (int o = 0; o < WPAD; ++o) {
            const float4 w = *(const float4*)&lwt[o * KPAD + k];
            float a = acc[o];
            a = fmaf(x0, w.x, a); a = fmaf(x1, w.y, a);
            a = fmaf(x2, w.z, a); a = fmaf(x3, w.w, a);
            acc[o] = a;
        }
    }
    if constexpr (KTAIL > 0) {
        const int k = K4 * 4;
        float xt[KTAIL];
#pragma unroll
        for (int t2 = 0; t2 < KTAIL; ++t2) xt[t2] = xr[k + t2];
#pragma unroll
        for (int o = 0; o < WPAD; ++o) {
            float a = acc[o];
#pragma unroll
            for (int t2 = 0; t2 < KTAIL; ++t2)
                a = fmaf(xt[t2], lwt[o * KPAD + k + t2], a);
            acc[o] = a;
        }
    }

    float* __restrict__ orow = out + (size_t)row * WPAD;
#pragma unroll
    for (int o = 0; o < WPAD; o += 4) {
        float4 v;
        v.x = DOELU ? elu1(acc[o + 0]) : acc[o + 0];
        v.y = DOELU ? elu1(acc[o + 1]) : acc[o + 1];
        v.z = DOELU ? elu1(acc[o + 2]) : acc[o + 2];
        v.w = DOELU ? elu1(acc[o + 3]) : acc[o + 3];
        *(float4*)&orow[o] = v;
    }
}

// ---------------------------------------------------------------------------
// Final projection: out[N,ODIM] = act[N,128] @ Wf + bf (+ x[:,1:5] for reg head)
// ---------------------------------------------------------------------------
template <int ODIM, bool ADDX>
__global__ __launch_bounds__(128, 2) void final_layer(
        const float* __restrict__ act,
        const float* __restrict__ wft,    // [ODIM][WPAD]
        const float* __restrict__ bf,
        const float* __restrict__ xin,
        float* __restrict__ outp) {
    __shared__ float lw[ODIM * WPAD];
    __shared__ float lb[ODIM];
    for (int t = threadIdx.x; t < ODIM * WPAD / 4; t += 128)
        ((float4*)lw)[t] = ((const float4*)wft)[t];
    if (threadIdx.x < ODIM) lb[threadIdx.x] = bf[threadIdx.x];
    __syncthreads();

    const int row = blockIdx.x * 128 + threadIdx.x;
    const float* __restrict__ ar = act + (size_t)row * WPAD;

    float acc[ODIM];
#pragma unroll
    for (int o = 0; o < ODIM; ++o) acc[o] = lb[o];

    for (int k4 = 0; k4 < WPAD / 4; ++k4) {
        const float4 xv = *(const float4*)&ar[k4 * 4];
#pragma unroll
        for (int o = 0; o < ODIM; ++o) {
            const float4 w = *(const float4*)&lw[o * WPAD + k4 * 4];
            float a = acc[o];
            a = fmaf(xv.x, w.x, a); a = fmaf(xv.y, w.y, a);
            a = fmaf(xv.z, w.z, a); a = fmaf(xv.w, w.w, a);
            acc[o] = a;
        }
    }
#pragma unroll
    for (int o = 0; o < ODIM; ++o) {
        float v = acc[o];
        if (ADDX) v += xin[(size_t)row * D_IN + 1 + o];
        outp[(size_t)row * ODIM + o] = v;
    }
}

// ---------------------------------------------------------------------------
extern "C" void kernel_launch(void* const* d_in, const int* in_sizes, int n_in,
                              void* d_out, int out_size, void* d_ws, size_t ws_size,
                              hipStream_t stream) {
    (void)in_sizes; (void)n_in; (void)out_size;

    const float* x   = (const float*)d_in[0];
    const float* cWs = (const float*)d_in[1];
    const float* cbs = (const float*)d_in[2];
    const float* cWh = (const float*)d_in[3];
    const float* cbh = (const float*)d_in[4];
    const float* cWo = (const float*)d_in[5];
    const float* cbo = (const float*)d_in[6];
    const float* hW0[3] = {(const float*)d_in[7],  (const float*)d_in[13], (const float*)d_in[19]};
    const float* hb0[3] = {(const float*)d_in[8],  (const float*)d_in[14], (const float*)d_in[20]};
    const float* hWh[3] = {(const float*)d_in[9],  (const float*)d_in[15], (const float*)d_in[21]};
    const float* hbh[3] = {(const float*)d_in[10], (const float*)d_in[16], (const float*)d_in[22]};
    const float* hWf[3] = {(const float*)d_in[11], (const float*)d_in[17], (const float*)d_in[23]};
    const float* hbf[3] = {(const float*)d_in[12], (const float*)d_in[18], (const float*)d_in[24]};
    float* outp = (float*)d_out;
    float* ws = (float*)d_ws;

    // workspace layout (floats)
    const size_t OFF_S    = 0;
    const size_t OFF_H    = OFF_S    + (size_t)N_NODES * 4;
    const size_t OFF_E1   = OFF_H    + (size_t)N_NODES * HPAD;
    const size_t OFF_E2   = OFF_E1   + (size_t)N_NODES * EPAD;
    const size_t OFF_AA   = OFF_E2   + (size_t)N_NODES * EPAD;
    const size_t OFF_AB   = OFF_AA   + (size_t)N_NODES * WPAD;
    const size_t OFF_W0T  = OFF_AB   + (size_t)N_NODES * WPAD;
    const size_t OFF_WHT0 = OFF_W0T  + 128 * 40;
    const size_t OFF_WHT1 = OFF_WHT0 + WPAD * WPAD;
    const size_t OFF_WFT  = OFF_WHT1 + WPAD * WPAD;
    const size_t WS_END   = OFF_WFT  + 8 * WPAD;
    if (ws_size < WS_END * sizeof(float)) return;  // leaves d_out poisoned -> clear failure

    float* s_buf = ws + OFF_S;
    float* h_buf = ws + OFF_H;
    float* emb1  = ws + OFF_E1;
    float* emb2  = ws + OFF_E2;
    float* act_a = ws + OFF_AA;
    float* act_b = ws + OFF_AB;
    float* w0t   = ws + OFF_W0T;
    float* wht0  = ws + OFF_WHT0;
    float* wht1  = ws + OFF_WHT1;
    float* wft   = ws + OFF_WFT;

    // ---- GravNet conv 1 (emb = x, stride 34) ----
    sh_kernel<<<256, 256, 0, stream>>>(x, D_IN, cWs, cbs, cWh, cbh, s_buf, h_buf);
    grav_kernel<<<256, 256, 0, stream>>>(x, D_IN, s_buf, h_buf, cWo, cbo, emb1);
    // ---- GravNet conv 2 ----
    sh_kernel<<<256, 256, 0, stream>>>(emb1, EPAD, cWs + EMB * S_DIM, cbs + S_DIM,
                                       cWh + EMB * P_DIM, cbh + P_DIM, s_buf, h_buf);
    grav_kernel<<<256, 256, 0, stream>>>(emb1, EPAD, s_buf, h_buf,
                                         cWo + CONCAT * EMB, cbo + EMB, emb2);

    // ---- heads ----
    const int odims[3] = {8, 4, 1};
    const size_t ooff[3] = {0, (size_t)N_NODES * 8, (size_t)N_NODES * 12};
    for (int hd = 0; hd < 3; ++hd) {
        prep_wt<<<(128 * 40 + 255) / 256, 256, 0, stream>>>(hW0[hd], w0t, D_IN, WIDTH, 40, 128 * 40);
        prep_wt<<<(WPAD * WPAD + 255) / 256, 256, 0, stream>>>(hWh[hd], wht0, WIDTH, WIDTH, WPAD, WPAD * WPAD);
        prep_wt<<<(WPAD * WPAD + 255) / 256, 256, 0, stream>>>(hWh[hd] + WIDTH * WIDTH, wht1, WIDTH, WIDTH, WPAD, WPAD * WPAD);
        prep_wt<<<(odims[hd] * WPAD + 255) / 256, 256, 0, stream>>>(hWf[hd], wft, WIDTH, odims[hd], WPAD, odims[hd] * WPAD);

        mlp_layer<8, 2, 40, true><<<512, 128, 0, stream>>>(emb2, EPAD, w0t, hb0[hd], act_a);
        mlp_layer<32, 0, 128, true><<<512, 128, 0, stream>>>(act_a, WPAD, wht0, hbh[hd], act_b);
        mlp_layer<32, 0, 128, true><<<512, 128, 0, stream>>>(act_b, WPAD, wht1, hbh[hd] + WIDTH, act_a);

        if (hd == 0)
            final_layer<8, false><<<512, 128, 0, stream>>>(act_a, wft, hbf[hd], x, outp + ooff[hd]);
        else if (hd == 1)
            final_layer<4, true><<<512, 128, 0, stream>>>(act_a, wft, hbf[hd], x, outp + ooff[hd]);
        else
            final_layer<1, false><<<512, 128, 0, stream>>>(act_a, wft, hbf[hd], x, outp + ooff[hd]);
    }
}

// Round 2
// 915.451 us; speedup vs baseline: 2.5427x; 2.5427x over previous
//
#include <hip/hip_runtime.h>
#include <math.h>

#define N_NODES 65536
#define NPG     4096
#define D_IN    34
#define EMB     34
#define S_DIM   4
#define P_DIM   22
#define CONCAT  78      // EMB + 2*P_DIM
#define WIDTH   126
#define KNN     8
#define HPAD    24      // padded h row (22 -> 24)
#define EPAD    36      // padded emb row (34 -> 36)
#define TILE    1024    // j-tile staged in LDS

__device__ __forceinline__ float elu1(float v) {
    return v > 0.f ? v : expm1f(v);
}

// ---------------------------------------------------------------------------
// s = emb @ Ws + bs   [N,4];   h = emb @ Wh + bh   [N,22] (stored padded to 24)
// ---------------------------------------------------------------------------
__global__ __launch_bounds__(256) void sh_kernel(
        const float* __restrict__ emb, int eld,
        const float* __restrict__ Ws, const float* __restrict__ bs,
        const float* __restrict__ Wh, const float* __restrict__ bh,
        float* __restrict__ s_out, float* __restrict__ h_out) {
    __shared__ float lWs[EMB * S_DIM];
    __shared__ float lWh[EMB * P_DIM];
    __shared__ float lbs[S_DIM];
    __shared__ float lbh[P_DIM];
    for (int t = threadIdx.x; t < EMB * S_DIM; t += 256) lWs[t] = Ws[t];
    for (int t = threadIdx.x; t < EMB * P_DIM; t += 256) lWh[t] = Wh[t];
    if (threadIdx.x < S_DIM) lbs[threadIdx.x] = bs[threadIdx.x];
    if (threadIdx.x < P_DIM) lbh[threadIdx.x] = bh[threadIdx.x];
    __syncthreads();

    const int n = blockIdx.x * 256 + threadIdx.x;
    const float* __restrict__ row = emb + (size_t)n * eld;
    float e[EMB];
#pragma unroll
    for (int r = 0; r < EMB; ++r) e[r] = row[r];

    float s[S_DIM], h[P_DIM];
#pragma unroll
    for (int c = 0; c < S_DIM; ++c) s[c] = lbs[c];
#pragma unroll
    for (int c = 0; c < P_DIM; ++c) h[c] = lbh[c];
#pragma unroll
    for (int r = 0; r < EMB; ++r) {
        const float er = e[r];
#pragma unroll
        for (int c = 0; c < S_DIM; ++c) s[c] = fmaf(er, lWs[r * S_DIM + c], s[c]);
#pragma unroll
        for (int c = 0; c < P_DIM; ++c) h[c] = fmaf(er, lWh[r * P_DIM + c], h[c]);
    }
    ((float4*)s_out)[n] = make_float4(s[0], s[1], s[2], s[3]);
    float* __restrict__ hr = h_out + (size_t)n * HPAD;
#pragma unroll
    for (int c = 0; c < P_DIM; ++c) hr[c] = h[c];
}

// ---------------------------------------------------------------------------
// GravNet: 4 threads per node (j-split, j = q mod 4), bitonic shfl merge,
// lane-split aggregation + output GEMM. grid = 16 graphs * 64 chunks.
// ELD = input emb leading dim; TOUT: write transposed [34][N] (for heads).
// ---------------------------------------------------------------------------
template <int ELD, bool TOUT>
__global__ __launch_bounds__(256, 4) void grav_kernel(
        const float* __restrict__ emb_in,
        const float* __restrict__ s_buf,
        const float* __restrict__ h_buf,
        const float* __restrict__ Wo, const float* __restrict__ bo,
        float* __restrict__ out) {
    __shared__ float4 sl[TILE];           // 16 KB j-tile of learned-space coords
    __shared__ float  wot[EMB * 80];      // Wo^T, rows padded 78 -> 80
    __shared__ float  bol[EMB];

    const int g     = blockIdx.x >> 6;    // 64 chunks per graph
    const int chunk = blockIdx.x & 63;
    const int gbase = g * NPG;
    const int tid   = threadIdx.x;
    const int q     = tid & 3;            // j-quarter
    const int il    = chunk * 64 + (tid >> 2);
    const int nglob = gbase + il;

    for (int t = tid; t < CONCAT * EMB; t += 256) {
        const int r = t / EMB, c = t % EMB;
        wot[c * 80 + r] = Wo[t];
    }
    if (tid < EMB) bol[tid] = bo[tid];

    const float4* __restrict__ sg = (const float4*)s_buf + gbase;
    float4 pre[4];
#pragma unroll
    for (int i = 0; i < 4; ++i) pre[i] = sg[tid + 256 * i];
    const float4 si = ((const float4*)s_buf)[nglob];

    float d[KNN]; int nb[KNN];
#pragma unroll
    for (int r = 0; r < KNN; ++r) { d[r] = 3.4e38f; nb[r] = 0; }

#pragma unroll
    for (int i = 0; i < 4; ++i) sl[tid + 256 * i] = pre[i];
    __syncthreads();

    for (int t = 0; t < NPG / TILE; ++t) {
        if (t < NPG / TILE - 1) {
#pragma unroll
            for (int i = 0; i < 4; ++i)
                pre[i] = sg[(t + 1) * TILE + tid + 256 * i];
        }
        const int jbase = t * TILE;
#pragma unroll 4
        for (int s = 0; s < TILE / 4; ++s) {
            const float4 sj = sl[4 * s + q];     // 4 bcast addrs, conflict-free
            const float dx = si.x - sj.x, dy = si.y - sj.y;
            const float dz = si.z - sj.z, dw = si.w - sj.w;
            const float d2 = fmaf(dx, dx, fmaf(dy, dy, fmaf(dz, dz, dw * dw)));
            if (d2 < d[0]) {                     // sift-insert, keeps desc order
                float cv = d2; int ci = jbase + 4 * s + q;
#pragma unroll
                for (int r = 0; r < KNN - 1; ++r) {
                    const float nx = d[r + 1]; const int ni = nb[r + 1];
                    const bool c = cv < nx;
                    d[r]  = c ? nx : cv;  nb[r] = c ? ni : ci;
                    cv    = c ? cv : nx;  ci    = c ? ci : ni;
                }
                d[KNN - 1] = cv; nb[KNN - 1] = ci;
            }
        }
        if (t < NPG / TILE - 1) {
            __syncthreads();
#pragma unroll
            for (int i = 0; i < 4; ++i) sl[tid + 256 * i] = pre[i];
            __syncthreads();
        }
    }

    // ---- merge 4 quarter-lists via bitonic min-merge over shfl_xor ----
    // total order T: (d asc, idx asc) lexicographic; lists sorted desc in T.
#pragma unroll
    for (int m = 1; m <= 2; m <<= 1) {
        float pd[KNN]; int pn[KNN];
#pragma unroll
        for (int r = 0; r < KNN; ++r) {
            pd[r] = __shfl_xor(d[r], m);
            pn[r] = __shfl_xor(nb[r], m);
        }
#pragma unroll
        for (int i = 0; i < KNN; ++i) {          // keep 8 T-smallest (bitonic half)
            const float od = pd[KNN - 1 - i]; const int on = pn[KNN - 1 - i];
            const bool take = (od < d[i]) || (od == d[i] && on < nb[i]);
            d[i]  = take ? od : d[i];
            nb[i] = take ? on : nb[i];
        }
#pragma unroll
        for (int s = 4; s >= 1; s >>= 1) {       // bitonic clean to desc
#pragma unroll
            for (int i = 0; i < KNN; ++i) {
                if ((i & s) == 0) {
                    const int j2 = i + s;
                    const bool sw = (d[i] < d[j2]) ||
                                    (d[i] == d[j2] && nb[i] < nb[j2]);
                    const float td = sw ? d[j2] : d[i];
                    const float bd = sw ? d[i] : d[j2];
                    const int   tn = sw ? nb[j2] : nb[i];
                    const int   bn = sw ? nb[i] : nb[j2];
                    d[i] = td; d[j2] = bd; nb[i] = tn; nb[j2] = bn;
                }
            }
        }
    }

    // ---- aggregation: each lane gathers 2 of the 8 neighbors, butterfly ----
    float macc[P_DIM], mmax[P_DIM];
#pragma unroll
    for (int c = 0; c < P_DIM; ++c) { macc[c] = 0.f; mmax[c] = -3.4e38f; }

#pragma unroll
    for (int rr = 0; rr < 2; ++rr) {
        const int r = 2 * q + rr;
        const float w = expf(-10.f * d[r]);
        const float4* __restrict__ hrow =
            (const float4*)(h_buf + (size_t)(gbase + nb[r]) * HPAD);
        const float4 q0 = hrow[0], q1 = hrow[1], q2 = hrow[2];
        const float4 q3 = hrow[3], q4 = hrow[4], q5 = hrow[5];
#define AGG(c, val) { const float mv = w * (val); macc[c] += mv; mmax[c] = fmaxf(mmax[c], mv); }
        AGG(0, q0.x) AGG(1, q0.y) AGG(2, q0.z) AGG(3, q0.w)
        AGG(4, q1.x) AGG(5, q1.y) AGG(6, q1.z) AGG(7, q1.w)
        AGG(8, q2.x) AGG(9, q2.y) AGG(10, q2.z) AGG(11, q2.w)
        AGG(12, q3.x) AGG(13, q3.y) AGG(14, q3.z) AGG(15, q3.w)
        AGG(16, q4.x) AGG(17, q4.y) AGG(18, q4.z) AGG(19, q4.w)
        AGG(20, q5.x) AGG(21, q5.y)
#undef AGG
    }
#pragma unroll
    for (int m = 1; m <= 2; m <<= 1) {
#pragma unroll
        for (int c = 0; c < P_DIM; ++c) {
            macc[c] += __shfl_xor(macc[c], m);
            mmax[c] = fmaxf(mmax[c], __shfl_xor(mmax[c], m));
        }
    }
#pragma unroll
    for (int c = 0; c < P_DIM; ++c) macc[c] *= 0.125f;

    // ---- fused output GEMM, cols split across the 4 lanes (c = q + 4m) ----
    float e[EMB];
    const float* __restrict__ erow = emb_in + (size_t)nglob * ELD;
    if constexpr (ELD == 34) {
#pragma unroll
        for (int i = 0; i < 17; ++i) {           // rows 136 B -> 8 B aligned
            const float2 v = ((const float2*)erow)[i];
            e[2 * i] = v.x; e[2 * i + 1] = v.y;
        }
    } else {
#pragma unroll
        for (int i = 0; i < 8; ++i) {            // rows 144 B -> 16 B aligned
            const float4 v = ((const float4*)erow)[i];
            e[4 * i] = v.x; e[4 * i + 1] = v.y; e[4 * i + 2] = v.z; e[4 * i + 3] = v.w;
        }
        const float2 v = ((const float2*)erow)[16];
        e[32] = v.x; e[33] = v.y;
    }

#pragma unroll
    for (int mcol = 0; mcol < 9; ++mcol) {
        const int c = q + 4 * mcol;
        if (c < EMB) {
            const float* __restrict__ wr = &wot[c * 80];
            float acc = bol[c];
#pragma unroll
            for (int r = 0; r < EMB; ++r)   acc = fmaf(e[r], wr[r], acc);
#pragma unroll
            for (int p = 0; p < P_DIM; ++p) acc = fmaf(macc[p], wr[34 + p], acc);
#pragma unroll
            for (int p = 0; p < P_DIM; ++p) acc = fmaf(mmax[p], wr[56 + p], acc);
            if constexpr (TOUT)
                out[(size_t)c * N_NODES + nglob] = acc;
            else
                out[(size_t)nglob * EPAD + c] = acc;
        }
    }
}

// ---------------------------------------------------------------------------
// Hidden MLP layer on transposed activations: outT[c][n] = act(inT @ W + b).
// Block = 256 thr covers 64 rows x 126 cols; wave w owns a 32-col slice ->
// weight addresses are wave-uniform (readfirstlane) -> scalar s_load path.
// x-tile staged once in LDS (read-once global traffic).
// ---------------------------------------------------------------------------
template <int K, bool DOELU>
__global__ __launch_bounds__(256, 4) void mlp_t(
        const float* __restrict__ inT,    // [K][N]
        const float* __restrict__ W,      // [K][126] natural layout
        const float* __restrict__ b,      // [126]
        float* __restrict__ outT) {       // [126][N]
    __shared__ float xs[K * 64];
    const int rowbase = blockIdx.x * 64;
    for (int t = threadIdx.x; t < K * 64; t += 256) {
        const int k = t >> 6, r = t & 63;
        xs[t] = inT[(size_t)k * N_NODES + rowbase + r];
    }
    __syncthreads();

    int colbase = __builtin_amdgcn_readfirstlane(threadIdx.x >> 6) * 32;
    if (colbase > WIDTH - 32) colbase = WIDTH - 32;   // wave 3: cols 94..125 (dup 94,95 benign)
    const int lane = threadIdx.x & 63;
    const int row  = rowbase + lane;

    float acc[32];
#pragma unroll
    for (int o = 0; o < 32; ++o) acc[o] = b[colbase + o];

#pragma unroll 2
    for (int k = 0; k < K; ++k) {
        const float xk = xs[k * 64 + lane];
        const float* __restrict__ wrow = W + (size_t)k * WIDTH + colbase;
#pragma unroll
        for (int o = 0; o < 32; ++o) acc[o] = fmaf(xk, wrow[o], acc[o]);
    }

#pragma unroll
    for (int o = 0; o < 32; ++o) {
        float v = acc[o];
        if (DOELU) v = elu1(v);
        outT[(size_t)(colbase + o) * N_NODES + row] = v;
    }
}

// ---------------------------------------------------------------------------
// Final projection from transposed activations; weights via uniform s_load.
// ---------------------------------------------------------------------------
template <int ODIM, bool ADDX>
__global__ __launch_bounds__(256) void final_t(
        const float* __restrict__ actT,   // [126][N]
        const float* __restrict__ Wf,     // [126][ODIM] natural layout
        const float* __restrict__ bf,
        const float* __restrict__ xin,
        float* __restrict__ outp) {
    const int row = blockIdx.x * 256 + threadIdx.x;
    float acc[ODIM];
#pragma unroll
    for (int o = 0; o < ODIM; ++o) acc[o] = bf[o];
#pragma unroll 2
    for (int k = 0; k < WIDTH; ++k) {
        const float a = actT[(size_t)k * N_NODES + row];
#pragma unroll
        for (int o = 0; o < ODIM; ++o) acc[o] = fmaf(a, Wf[k * ODIM + o], acc[o]);
    }
#pragma unroll
    for (int o = 0; o < ODIM; ++o) {
        float v = acc[o];
        if (ADDX) v += xin[(size_t)row * D_IN + 1 + o];
        outp[(size_t)row * ODIM + o] = v;
    }
}

// ---------------------------------------------------------------------------
extern "C" void kernel_launch(void* const* d_in, const int* in_sizes, int n_in,
                              void* d_out, int out_size, void* d_ws, size_t ws_size,
                              hipStream_t stream) {
    (void)in_sizes; (void)n_in; (void)out_size;

    const float* x   = (const float*)d_in[0];
    const float* cWs = (const float*)d_in[1];
    const float* cbs = (const float*)d_in[2];
    const float* cWh = (const float*)d_in[3];
    const float* cbh = (const float*)d_in[4];
    const float* cWo = (const float*)d_in[5];
    const float* cbo = (const float*)d_in[6];
    const float* hW0[3] = {(const float*)d_in[7],  (const float*)d_in[13], (const float*)d_in[19]};
    const float* hb0[3] = {(const float*)d_in[8],  (const float*)d_in[14], (const float*)d_in[20]};
    const float* hWh[3] = {(const float*)d_in[9],  (const float*)d_in[15], (const float*)d_in[21]};
    const float* hbh[3] = {(const float*)d_in[10], (const float*)d_in[16], (const float*)d_in[22]};
    const float* hWf[3] = {(const float*)d_in[11], (const float*)d_in[17], (const float*)d_in[23]};
    const float* hbf[3] = {(const float*)d_in[12], (const float*)d_in[18], (const float*)d_in[24]};
    float* outp = (float*)d_out;
    float* ws = (float*)d_ws;

    // workspace layout (floats)
    const size_t OFF_S   = 0;
    const size_t OFF_H   = OFF_S   + (size_t)N_NODES * 4;
    const size_t OFF_E1  = OFF_H   + (size_t)N_NODES * HPAD;
    const size_t OFF_E2T = OFF_E1  + (size_t)N_NODES * EPAD;
    const size_t OFF_AA  = OFF_E2T + (size_t)EMB * N_NODES;
    const size_t OFF_AB  = OFF_AA  + (size_t)WIDTH * N_NODES;
    const size_t WS_END  = OFF_AB  + (size_t)WIDTH * N_NODES;
    if (ws_size < WS_END * sizeof(float)) return;

    float* s_buf  = ws + OFF_S;
    float* h_buf  = ws + OFF_H;
    float* emb1   = ws + OFF_E1;
    float* emb2T  = ws + OFF_E2T;
    float* act_a  = ws + OFF_AA;
    float* act_b  = ws + OFF_AB;

    // ---- GravNet conv 1 (emb = x, row-major out) ----
    sh_kernel<<<256, 256, 0, stream>>>(x, D_IN, cWs, cbs, cWh, cbh, s_buf, h_buf);
    grav_kernel<34, false><<<1024, 256, 0, stream>>>(x, s_buf, h_buf, cWo, cbo, emb1);
    // ---- GravNet conv 2 (transposed out for heads) ----
    sh_kernel<<<256, 256, 0, stream>>>(emb1, EPAD, cWs + EMB * S_DIM, cbs + S_DIM,
                                       cWh + EMB * P_DIM, cbh + P_DIM, s_buf, h_buf);
    grav_kernel<36, true><<<1024, 256, 0, stream>>>(emb1, s_buf, h_buf,
                                                    cWo + CONCAT * EMB, cbo + EMB, emb2T);

    // ---- heads ----
    const size_t ooff[3] = {0, (size_t)N_NODES * 8, (size_t)N_NODES * 12};
    for (int hd = 0; hd < 3; ++hd) {
        mlp_t<EMB, true><<<1024, 256, 0, stream>>>(emb2T, hW0[hd], hb0[hd], act_a);
        mlp_t<WIDTH, true><<<1024, 256, 0, stream>>>(act_a, hWh[hd], hbh[hd], act_b);
        mlp_t<WIDTH, true><<<1024, 256, 0, stream>>>(act_b, hWh[hd] + WIDTH * WIDTH,
                                                     hbh[hd] + WIDTH, act_a);
        if (hd == 0)
            final_t<8, false><<<256, 256, 0, stream>>>(act_a, hWf[hd], hbf[hd], x, outp + ooff[hd]);
        else if (hd == 1)
            final_t<4, true><<<256, 256, 0, stream>>>(act_a, hWf[hd], hbf[hd], x, outp + ooff[hd]);
        else
            final_t<1, false><<<256, 256, 0, stream>>>(act_a, hWf[hd], hbf[hd], x, outp + ooff[hd]);
    }
}

// Round 3
// 873.544 us; speedup vs baseline: 2.6647x; 1.0480x over previous
//
#include <hip/hip_runtime.h>
#include <math.h>

#define N_NODES 65536
#define NPG     4096
#define D_IN    34
#define EMB     34
#define S_DIM   4
#define P_DIM   22
#define CONCAT  78      // EMB + 2*P_DIM
#define WIDTH   126
#define KNN     8
#define HPAD    24      // padded h row (22 -> 24)
#define EPAD    36      // padded emb row (34 -> 36)
#define TILE    1024    // j-tile staged in LDS

__device__ __forceinline__ float elu1(float v) {
    return v > 0.f ? v : expm1f(v);
}

// ---------------------------------------------------------------------------
// s = emb @ Ws + bs   [N,4];   h = emb @ Wh + bh   [N,22] (stored padded to 24)
// ---------------------------------------------------------------------------
__global__ __launch_bounds__(256) void sh_kernel(
        const float* __restrict__ emb, int eld,
        const float* __restrict__ Ws, const float* __restrict__ bs,
        const float* __restrict__ Wh, const float* __restrict__ bh,
        float* __restrict__ s_out, float* __restrict__ h_out) {
    __shared__ float lWs[EMB * S_DIM];
    __shared__ float lWh[EMB * P_DIM];
    __shared__ float lbs[S_DIM];
    __shared__ float lbh[P_DIM];
    for (int t = threadIdx.x; t < EMB * S_DIM; t += 256) lWs[t] = Ws[t];
    for (int t = threadIdx.x; t < EMB * P_DIM; t += 256) lWh[t] = Wh[t];
    if (threadIdx.x < S_DIM) lbs[threadIdx.x] = bs[threadIdx.x];
    if (threadIdx.x < P_DIM) lbh[threadIdx.x] = bh[threadIdx.x];
    __syncthreads();

    const int n = blockIdx.x * 256 + threadIdx.x;
    const float* __restrict__ row = emb + (size_t)n * eld;
    float e[EMB];
#pragma unroll
    for (int r = 0; r < EMB; ++r) e[r] = row[r];

    float s[S_DIM], h[P_DIM];
#pragma unroll
    for (int c = 0; c < S_DIM; ++c) s[c] = lbs[c];
#pragma unroll
    for (int c = 0; c < P_DIM; ++c) h[c] = lbh[c];
#pragma unroll
    for (int r = 0; r < EMB; ++r) {
        const float er = e[r];
#pragma unroll
        for (int c = 0; c < S_DIM; ++c) s[c] = fmaf(er, lWs[r * S_DIM + c], s[c]);
#pragma unroll
        for (int c = 0; c < P_DIM; ++c) h[c] = fmaf(er, lWh[r * P_DIM + c], h[c]);
    }
    ((float4*)s_out)[n] = make_float4(s[0], s[1], s[2], s[3]);
    float* __restrict__ hr = h_out + (size_t)n * HPAD;
#pragma unroll
    for (int c = 0; c < P_DIM; ++c) hr[c] = h[c];
}

// ---------------------------------------------------------------------------
// GravNet v3: two-phase kNN.
//  Phase A: branchless distance-only top-8 (bubble-insert, 15 min/max ops),
//           bitonic d-only merge across the 4 j-split lanes -> d8 threshold.
//  Phase B: rescan, collect (d2, j) with d2 <= d8 into per-node LDS buffer
//           (atomic slot). ~8 hits per node -> divergence is genuinely rare.
//  Epilogue: canonical sort-by-j (determinism), aggregate, fused output GEMM.
// grid = 16 graphs * 64 chunks; block = 256 thr = 64 nodes x 4 lanes.
// ---------------------------------------------------------------------------
template <int ELD, bool TOUT>
__global__ __launch_bounds__(256, 4) void grav_kernel(
        const float* __restrict__ emb_in,
        const float* __restrict__ s_buf,
        const float* __restrict__ h_buf,
        const float* __restrict__ Wo, const float* __restrict__ bo,
        float* __restrict__ out) {
    __shared__ float4 sl[TILE];           // 16 KB j-tile of learned-space coords
    __shared__ float  wot[EMB * 80];      // Wo^T, rows padded 78 -> 80
    __shared__ float  bol[EMB];
    __shared__ float  bufd[64][17];       // phase-B candidate distances
    __shared__ int    bufj[64][17];       // phase-B candidate indices
    __shared__ int    cnt[64];

    const int g     = blockIdx.x >> 6;    // 64 chunks per graph
    const int chunk = blockIdx.x & 63;
    const int gbase = g * NPG;
    const int tid   = threadIdx.x;
    const int q     = tid & 3;            // j-quarter
    const int nl    = tid >> 2;           // node-local (0..63)
    const int il    = chunk * 64 + nl;    // node index within graph
    const int nglob = gbase + il;

    for (int t = tid; t < CONCAT * EMB; t += 256) {
        const int r = t / EMB, c = t % EMB;
        wot[c * 80 + r] = Wo[t];
    }
    if (tid < EMB) bol[tid] = bo[tid];
    if (tid < 64) cnt[tid] = 0;

    const float4* __restrict__ sg = (const float4*)s_buf + gbase;
    float4 pre[4];
#pragma unroll
    for (int i = 0; i < 4; ++i) pre[i] = sg[tid + 256 * i];
    const float4 si = ((const float4*)s_buf)[nglob];

    float d[KNN];
#pragma unroll
    for (int r = 0; r < KNN; ++r) d[r] = 3.4e38f;

#pragma unroll
    for (int i = 0; i < 4; ++i) sl[tid + 256 * i] = pre[i];
    __syncthreads();

    // ================= Phase A: branchless threshold scan ==================
    for (int t = 0; t < NPG / TILE; ++t) {
        if (t < NPG / TILE - 1) {
#pragma unroll
            for (int i = 0; i < 4; ++i)
                pre[i] = sg[(t + 1) * TILE + tid + 256 * i];
        }
#pragma unroll 4
        for (int s = 0; s < TILE / 4; ++s) {
            const float4 sj = sl[4 * s + q];     // 4 bcast addrs, conflict-free
            const float dx = si.x - sj.x, dy = si.y - sj.y;
            const float dz = si.z - sj.z, dw = si.w - sj.w;
            const float d2 = fmaf(dx, dx, fmaf(dy, dy, fmaf(dz, dz, dw * dw)));
            // bubble-insert into sorted-desc d[0..7]; no-op when d2 >= d[0]
            float c = fminf(d2, d[0]);
#pragma unroll
            for (int r = KNN - 1; r >= 1; --r) {
                const float hi = fmaxf(d[r], c);
                d[r] = fminf(d[r], c);
                c = hi;
            }
            d[0] = c;
        }
        if (t < NPG / TILE - 1) {
            __syncthreads();
#pragma unroll
            for (int i = 0; i < 4; ++i) sl[tid + 256 * i] = pre[i];
            __syncthreads();
        }
    }

    // ---- d-only bitonic merge of the 4 quarter-lists -> global 8th-smallest
#pragma unroll
    for (int mrk = 1; mrk <= 2; mrk <<= 1) {
        float p[KNN];
#pragma unroll
        for (int r = 0; r < KNN; ++r) p[r] = __shfl_xor(d[r], mrk);
        float z[KNN];
#pragma unroll
        for (int i = 0; i < KNN; ++i) z[i] = fminf(d[i], p[KNN - 1 - i]);
#pragma unroll
        for (int s2 = 4; s2 >= 1; s2 >>= 1) {
#pragma unroll
            for (int i = 0; i < KNN; ++i) {
                if ((i & s2) == 0) {
                    const float hi = fmaxf(z[i], z[i + s2]);
                    const float lo = fminf(z[i], z[i + s2]);
                    z[i] = hi; z[i + s2] = lo;
                }
            }
        }
#pragma unroll
        for (int r = 0; r < KNN; ++r) d[r] = z[r];
    }
    const float d8 = d[0];               // 8th-smallest distance (threshold)

    // ================= Phase B: collect the <= d8 candidates ===============
    for (int t = 0; t < NPG / TILE; ++t) {
        __syncthreads();
#pragma unroll
        for (int i = 0; i < 4; ++i)
            sl[tid + 256 * i] = sg[t * TILE + tid + 256 * i];
        __syncthreads();
        const int jbase = t * TILE;
#pragma unroll 4
        for (int s = 0; s < TILE / 4; ++s) {
            const float4 sj = sl[4 * s + q];
            const float dx = si.x - sj.x, dy = si.y - sj.y;
            const float dz = si.z - sj.z, dw = si.w - sj.w;
            const float d2 = fmaf(dx, dx, fmaf(dy, dy, fmaf(dz, dz, dw * dw)));
            if (d2 <= d8) {
                const int slot = atomicAdd(&cnt[nl], 1);
                if (slot < 16) {
                    bufd[nl][slot] = d2;
                    bufj[nl][slot] = jbase + 4 * s + q;
                }
            }
        }
    }
    __syncthreads();

    // ---- tie case (cnt > 8, ~never): keep 8 smallest by (d2, j) ----------
    const int m = cnt[nl];
    if (m > 8 && q == 0) {
        const int mm = m < 16 ? m : 16;
        for (int a = 0; a < 8; ++a) {
            int best = a;
            for (int b2 = a + 1; b2 < mm; ++b2) {
                const float db = bufd[nl][b2], da = bufd[nl][best];
                if (db < da || (db == da && bufj[nl][b2] < bufj[nl][best]))
                    best = b2;
            }
            const float td = bufd[nl][a]; bufd[nl][a] = bufd[nl][best]; bufd[nl][best] = td;
            const int   tj = bufj[nl][a]; bufj[nl][a] = bufj[nl][best]; bufj[nl][best] = tj;
        }
    }
    __syncthreads();

    // ---- canonical order (sort 8 by j asc) for determinism ----------------
    float ed[8]; int ej[8];
#pragma unroll
    for (int t = 0; t < 8; ++t) { ed[t] = bufd[nl][t]; ej[t] = bufj[nl][t]; }
#define CASJ(a, b) { if (ej[a] > ej[b]) { const int tj = ej[a]; ej[a] = ej[b]; ej[b] = tj; \
                                          const float td = ed[a]; ed[a] = ed[b]; ed[b] = td; } }
    CASJ(0,1) CASJ(2,3) CASJ(4,5) CASJ(6,7)
    CASJ(0,2) CASJ(1,3) CASJ(4,6) CASJ(5,7)
    CASJ(1,2) CASJ(5,6)
    CASJ(0,4) CASJ(1,5) CASJ(2,6) CASJ(3,7)
    CASJ(2,4) CASJ(3,5)
    CASJ(1,2) CASJ(3,4) CASJ(5,6)
#undef CASJ
    // lane q handles entries q and q+4 (static extraction, no runtime indexing)
    const float dA = q == 0 ? ed[0] : q == 1 ? ed[1] : q == 2 ? ed[2] : ed[3];
    const int   jA = q == 0 ? ej[0] : q == 1 ? ej[1] : q == 2 ? ej[2] : ej[3];
    const float dB = q == 0 ? ed[4] : q == 1 ? ed[5] : q == 2 ? ed[6] : ed[7];
    const int   jB = q == 0 ? ej[4] : q == 1 ? ej[5] : q == 2 ? ej[6] : ej[7];

    // ---- aggregation: 2 neighbors per lane, butterfly over 4 lanes --------
    float macc[P_DIM], mmax[P_DIM];
#pragma unroll
    for (int c = 0; c < P_DIM; ++c) { macc[c] = 0.f; mmax[c] = -3.4e38f; }

#pragma unroll
    for (int rr = 0; rr < 2; ++rr) {
        const float w = expf(-10.f * (rr == 0 ? dA : dB));
        const int   j = rr == 0 ? jA : jB;
        const float4* __restrict__ hrow =
            (const float4*)(h_buf + (size_t)(gbase + j) * HPAD);
        const float4 q0 = hrow[0], q1 = hrow[1], q2 = hrow[2];
        const float4 q3 = hrow[3], q4 = hrow[4], q5 = hrow[5];
#define AGG(c, val) { const float mv = w * (val); macc[c] += mv; mmax[c] = fmaxf(mmax[c], mv); }
        AGG(0, q0.x) AGG(1, q0.y) AGG(2, q0.z) AGG(3, q0.w)
        AGG(4, q1.x) AGG(5, q1.y) AGG(6, q1.z) AGG(7, q1.w)
        AGG(8, q2.x) AGG(9, q2.y) AGG(10, q2.z) AGG(11, q2.w)
        AGG(12, q3.x) AGG(13, q3.y) AGG(14, q3.z) AGG(15, q3.w)
        AGG(16, q4.x) AGG(17, q4.y) AGG(18, q4.z) AGG(19, q4.w)
        AGG(20, q5.x) AGG(21, q5.y)
#undef AGG
    }
#pragma unroll
    for (int mrk = 1; mrk <= 2; mrk <<= 1) {
#pragma unroll
        for (int c = 0; c < P_DIM; ++c) {
            macc[c] += __shfl_xor(macc[c], mrk);
            mmax[c] = fmaxf(mmax[c], __shfl_xor(mmax[c], mrk));
        }
    }
#pragma unroll
    for (int c = 0; c < P_DIM; ++c) macc[c] *= 0.125f;

    // ---- fused output GEMM, cols split across the 4 lanes (c = q + 4m) ----
    float e[EMB];
    const float* __restrict__ erow = emb_in + (size_t)nglob * ELD;
    if constexpr (ELD == 34) {
#pragma unroll
        for (int i = 0; i < 17; ++i) {           // rows 136 B -> 8 B aligned
            const float2 v = ((const float2*)erow)[i];
            e[2 * i] = v.x; e[2 * i + 1] = v.y;
        }
    } else {
#pragma unroll
        for (int i = 0; i < 8; ++i) {            // rows 144 B -> 16 B aligned
            const float4 v = ((const float4*)erow)[i];
            e[4 * i] = v.x; e[4 * i + 1] = v.y; e[4 * i + 2] = v.z; e[4 * i + 3] = v.w;
        }
        const float2 v = ((const float2*)erow)[16];
        e[32] = v.x; e[33] = v.y;
    }

#pragma unroll
    for (int mcol = 0; mcol < 9; ++mcol) {
        const int c = q + 4 * mcol;
        if (c < EMB) {
            const float* __restrict__ wr = &wot[c * 80];
            float acc = bol[c];
#pragma unroll
            for (int r = 0; r < EMB; ++r)   acc = fmaf(e[r], wr[r], acc);
#pragma unroll
            for (int p = 0; p < P_DIM; ++p) acc = fmaf(macc[p], wr[34 + p], acc);
#pragma unroll
            for (int p = 0; p < P_DIM; ++p) acc = fmaf(mmax[p], wr[56 + p], acc);
            if constexpr (TOUT)
                out[(size_t)c * N_NODES + nglob] = acc;
            else
                out[(size_t)nglob * EPAD + c] = acc;
        }
    }
}

// ---------------------------------------------------------------------------
// Hidden MLP layer on transposed activations: outT[c][n] = act(inT @ W + b).
// ---------------------------------------------------------------------------
template <int K, bool DOELU>
__global__ __launch_bounds__(256, 4) void mlp_t(
        const float* __restrict__ inT,    // [K][N]
        const float* __restrict__ W,      // [K][126] natural layout
        const float* __restrict__ b,      // [126]
        float* __restrict__ outT) {       // [126][N]
    __shared__ float xs[K * 64];
    const int rowbase = blockIdx.x * 64;
    for (int t = threadIdx.x; t < K * 64; t += 256) {
        const int k = t >> 6, r = t & 63;
        xs[t] = inT[(size_t)k * N_NODES + rowbase + r];
    }
    __syncthreads();

    int colbase = __builtin_amdgcn_readfirstlane(threadIdx.x >> 6) * 32;
    if (colbase > WIDTH - 32) colbase = WIDTH - 32;   // wave 3: cols 94..125
    const int lane = threadIdx.x & 63;
    const int row  = rowbase + lane;

    float acc[32];
#pragma unroll
    for (int o = 0; o < 32; ++o) acc[o] = b[colbase + o];

#pragma unroll 2
    for (int k = 0; k < K; ++k) {
        const float xk = xs[k * 64 + lane];
        const float* __restrict__ wrow = W + (size_t)k * WIDTH + colbase;
#pragma unroll
        for (int o = 0; o < 32; ++o) acc[o] = fmaf(xk, wrow[o], acc[o]);
    }

#pragma unroll
    for (int o = 0; o < 32; ++o) {
        float v = acc[o];
        if (DOELU) v = elu1(v);
        outT[(size_t)(colbase + o) * N_NODES + row] = v;
    }
}

// ---------------------------------------------------------------------------
// Final projection from transposed activations.
// ---------------------------------------------------------------------------
template <int ODIM, bool ADDX>
__global__ __launch_bounds__(256) void final_t(
        const float* __restrict__ actT,   // [126][N]
        const float* __restrict__ Wf,     // [126][ODIM] natural layout
        const float* __restrict__ bf,
        const float* __restrict__ xin,
        float* __restrict__ outp) {
    const int row = blockIdx.x * 256 + threadIdx.x;
    float acc[ODIM];
#pragma unroll
    for (int o = 0; o < ODIM; ++o) acc[o] = bf[o];
#pragma unroll 2
    for (int k = 0; k < WIDTH; ++k) {
        const float a = actT[(size_t)k * N_NODES + row];
#pragma unroll
        for (int o = 0; o < ODIM; ++o) acc[o] = fmaf(a, Wf[k * ODIM + o], acc[o]);
    }
#pragma unroll
    for (int o = 0; o < ODIM; ++o) {
        float v = acc[o];
        if (ADDX) v += xin[(size_t)row * D_IN + 1 + o];
        outp[(size_t)row * ODIM + o] = v;
    }
}

// ---------------------------------------------------------------------------
extern "C" void kernel_launch(void* const* d_in, const int* in_sizes, int n_in,
                              void* d_out, int out_size, void* d_ws, size_t ws_size,
                              hipStream_t stream) {
    (void)in_sizes; (void)n_in; (void)out_size;

    const float* x   = (const float*)d_in[0];
    const float* cWs = (const float*)d_in[1];
    const float* cbs = (const float*)d_in[2];
    const float* cWh = (const float*)d_in[3];
    const float* cbh = (const float*)d_in[4];
    const float* cWo = (const float*)d_in[5];
    const float* cbo = (const float*)d_in[6];
    const float* hW0[3] = {(const float*)d_in[7],  (const float*)d_in[13], (const float*)d_in[19]};
    const float* hb0[3] = {(const float*)d_in[8],  (const float*)d_in[14], (const float*)d_in[20]};
    const float* hWh[3] = {(const float*)d_in[9],  (const float*)d_in[15], (const float*)d_in[21]};
    const float* hbh[3] = {(const float*)d_in[10], (const float*)d_in[16], (const float*)d_in[22]};
    const float* hWf[3] = {(const float*)d_in[11], (const float*)d_in[17], (const float*)d_in[23]};
    const float* hbf[3] = {(const float*)d_in[12], (const float*)d_in[18], (const float*)d_in[24]};
    float* outp = (float*)d_out;
    float* ws = (float*)d_ws;

    // workspace layout (floats)
    const size_t OFF_S   = 0;
    const size_t OFF_H   = OFF_S   + (size_t)N_NODES * 4;
    const size_t OFF_E1  = OFF_H   + (size_t)N_NODES * HPAD;
    const size_t OFF_E2T = OFF_E1  + (size_t)N_NODES * EPAD;
    const size_t OFF_AA  = OFF_E2T + (size_t)EMB * N_NODES;
    const size_t OFF_AB  = OFF_AA  + (size_t)WIDTH * N_NODES;
    const size_t WS_END  = OFF_AB  + (size_t)WIDTH * N_NODES;
    if (ws_size < WS_END * sizeof(float)) return;

    float* s_buf  = ws + OFF_S;
    float* h_buf  = ws + OFF_H;
    float* emb1   = ws + OFF_E1;
    float* emb2T  = ws + OFF_E2T;
    float* act_a  = ws + OFF_AA;
    float* act_b  = ws + OFF_AB;

    // ---- GravNet conv 1 (emb = x, row-major out) ----
    sh_kernel<<<256, 256, 0, stream>>>(x, D_IN, cWs, cbs, cWh, cbh, s_buf, h_buf);
    grav_kernel<34, false><<<1024, 256, 0, stream>>>(x, s_buf, h_buf, cWo, cbo, emb1);
    // ---- GravNet conv 2 (transposed out for heads) ----
    sh_kernel<<<256, 256, 0, stream>>>(emb1, EPAD, cWs + EMB * S_DIM, cbs + S_DIM,
                                       cWh + EMB * P_DIM, cbh + P_DIM, s_buf, h_buf);
    grav_kernel<36, true><<<1024, 256, 0, stream>>>(emb1, s_buf, h_buf,
                                                    cWo + CONCAT * EMB, cbo + EMB, emb2T);

    // ---- heads ----
    const size_t ooff[3] = {0, (size_t)N_NODES * 8, (size_t)N_NODES * 12};
    for (int hd = 0; hd < 3; ++hd) {
        mlp_t<EMB, true><<<1024, 256, 0, stream>>>(emb2T, hW0[hd], hb0[hd], act_a);
        mlp_t<WIDTH, true><<<1024, 256, 0, stream>>>(act_a, hWh[hd], hbh[hd], act_b);
        mlp_t<WIDTH, true><<<1024, 256, 0, stream>>>(act_b, hWh[hd] + WIDTH * WIDTH,
                                                     hbh[hd] + WIDTH, act_a);
        if (hd == 0)
            final_t<8, false><<<256, 256, 0, stream>>>(act_a, hWf[hd], hbf[hd], x, outp + ooff[hd]);
        else if (hd == 1)
            final_t<4, true><<<256, 256, 0, stream>>>(act_a, hWf[hd], hbf[hd], x, outp + ooff[hd]);
        else
            final_t<1, false><<<256, 256, 0, stream>>>(act_a, hWf[hd], hbf[hd], x, outp + ooff[hd]);
    }
}